// Round 15
// baseline (179.271 us; speedup 1.0000x reference)
//
#include <hip/hip_runtime.h>
#include <hip/hip_bf16.h>

// MoE MLP: x[1,2048,768] fp32, router_w[16,768], w1[768,12288], w2[12288,768]
// out[1,2048,768] fp32.  Experts: 8x512 + 8x1024, top-8, normalized.
// Dense bf16 GEMMs (reference is dense+masked); comb folded into H.
// GEMM core: m201 8-phase structure x R8 affine addressing. 256x256 tile,
// BK=64, 8 waves (2Mx4N, 128x64/wave), 128KB dbuf LDS. Loop iter = 2 K-tiles
// (parity compile-time). Per K-tile 4 phases ({12,4,8,0} ds_reads + 2 gloads
// each): [lgkm(8)] -> barrier -> lgkmcnt(0) -> sched_barrier -> setprio ->
// 16 MFMA -> setprio -> barrier. Stage stream: A(t+1)@P1-2 -> buf p^1,
// B(t+2)@P3-4 -> buf p. One counted vmcnt(4) per K-tile at P4 (queue depth
// 12: keeps B(t+2)'s 4 loads in flight, drains through A(t+1)). All LDS
// addresses are base+immediate; 8 affine global pointers, +256B per iter;
// unconditional tail stages land in adjacent ws regions (never read).

#define T_TOK 2048
#define D_EMB 768
#define W_TOT 12288
#define N_EXP 16

typedef __attribute__((ext_vector_type(4))) float f32x4;
typedef __attribute__((ext_vector_type(8))) short bf16x8;

typedef __attribute__((address_space(1))) const unsigned int as1c_u32;
typedef __attribute__((address_space(3))) unsigned int as3_u32;

__device__ __forceinline__ void gload16(const void* g, void* l) {
  __builtin_amdgcn_global_load_lds((as1c_u32*)g, (as3_u32*)l, 16, 0, 0);
}

__device__ __forceinline__ unsigned short f2bf(float f) {
  __hip_bfloat16 h = __float2bfloat16(f);
  return *reinterpret_cast<unsigned short*>(&h);
}

__device__ __forceinline__ float gelu_f(float x) {
  // jax.nn.gelu default (approximate=True, tanh form)
  float x3 = x * x * x;
  float a = 0.7978845608028654f * __builtin_fmaf(0.044715f, x3, x);
  a = fminf(fmaxf(a, -20.f), 20.f);
  float e = __expf(-2.0f * a);
  float t = (1.0f - e) / (1.0f + e);
  return 0.5f * x * (1.0f + t);
}

// in fp32 [R][C] -> out bf16 [C][R]
__global__ __launch_bounds__(256) void transpose_cvt_kernel(
    const float* __restrict__ in, unsigned short* __restrict__ out, int R, int C) {
  __shared__ float tile[32][33];
  int c0 = blockIdx.x * 32;
  int r0 = blockIdx.y * 32;
  int i = threadIdx.x;
  {
    int r = i >> 3, c4 = (i & 7) * 4;
    float4 v = *(const float4*)(in + (size_t)(r0 + r) * C + c0 + c4);
    tile[r][c4 + 0] = v.x; tile[r][c4 + 1] = v.y;
    tile[r][c4 + 2] = v.z; tile[r][c4 + 3] = v.w;
  }
  __syncthreads();
  {
    int c = i >> 3, r4 = (i & 7) * 4;
    ushort4 o;
    o.x = f2bf(tile[r4 + 0][c]);
    o.y = f2bf(tile[r4 + 1][c]);
    o.z = f2bf(tile[r4 + 2][c]);
    o.w = f2bf(tile[r4 + 3][c]);
    *(ushort4*)(out + (size_t)(c0 + c) * R + r0 + r4) = o;
  }
}

// ---------------- router (also emits xb = bf16(x)) ----------------

__global__ __launch_bounds__(256) void router_kernel(
    const float* __restrict__ x, const float* __restrict__ rw,
    float* __restrict__ comb, unsigned short* __restrict__ xbout) {
  int tid = threadIdx.x, lane = tid & 63, w = tid >> 6;
  int t = blockIdx.x * 4 + w;
  const float* xr = x + (size_t)t * D_EMB;
  float xv[12];
#pragma unroll
  for (int i = 0; i < 12; ++i) xv[i] = xr[lane + 64 * i];
#pragma unroll
  for (int i = 0; i < 12; ++i)
    xbout[(size_t)t * D_EMB + lane + 64 * i] = f2bf(xv[i]);
  float lg[16];
#pragma unroll
  for (int e = 0; e < 16; ++e) {
    const float* we = rw + (size_t)e * D_EMB;
    float p = 0.f;
#pragma unroll
    for (int i = 0; i < 12; ++i) p = __builtin_fmaf(xv[i], we[lane + 64 * i], p);
#pragma unroll
    for (int off = 32; off >= 1; off >>= 1) p += __shfl_xor(p, off, 64);
    lg[e] = p;
  }
  float mx = lg[0];
#pragma unroll
  for (int e = 1; e < 16; ++e) mx = fmaxf(mx, lg[e]);
  float ex[16];
#pragma unroll
  for (int e = 0; e < 16; ++e) ex[e] = __expf(lg[e] - mx);
  float selsum = 0.f, myval = 0.f;
#pragma unroll
  for (int e = 0; e < 16; ++e) {
    int rank = 0;
#pragma unroll
    for (int e2 = 0; e2 < 16; ++e2)
      rank += (ex[e2] > ex[e]) || (ex[e2] == ex[e] && e2 < e);
    bool sel = rank < 8;
    float v = sel ? ex[e] : 0.f;
    selsum += v;
    if (e == lane) myval = v;
  }
  if (lane < 16) comb[(size_t)t * N_EXP + lane] = myval / selsum;
}

// ---------------- 8-wave 8-phase GEMM, 256x256 tile, BK=64 ----------------
// MAP: 0 = gemm1 XCD-owns-6-N-panels (grid 384), 1 = gemm2 XCD=zt (grid 192).
// EPI: 1 = gelu*comb -> bf16 H, 0 = fp32 partial.

#define MFMA8(AM, NN, A0, A1, B0, B1)                                           \
  _Pragma("unroll") for (int m = 0; m < 4; ++m)                                 \
    _Pragma("unroll") for (int n = 0; n < 2; ++n) {                             \
      acc[(AM) + m][(NN) + n] = __builtin_amdgcn_mfma_f32_16x16x32_bf16(        \
          A0[m], B0[n], acc[(AM) + m][(NN) + n], 0, 0, 0);                      \
      acc[(AM) + m][(NN) + n] = __builtin_amdgcn_mfma_f32_16x16x32_bf16(        \
          A1[m], B1[n], acc[(AM) + m][(NN) + n], 0, 0, 0);                      \
    }

#define KTILE(P)                                                                \
  { /* P1: read a(m0-3)+bLo (12 ds); stage A(t+1)h0 -> buf P^1 */               \
    _Pragma("unroll") for (int m = 0; m < 4; ++m) {                             \
      aC0[m] = *(const bf16x8*)(smem + (P)*32768 + ab0 + m * 2048);             \
      aC1[m] = *(const bf16x8*)(smem + (P)*32768 + ab1 + m * 2048);             \
    }                                                                           \
    _Pragma("unroll") for (int n = 0; n < 2; ++n) {                             \
      bL0[n] = *(const bf16x8*)(smem + 65536 + (P)*32768 + bb0 + n * 2048);     \
      bL1[n] = *(const bf16x8*)(smem + 65536 + (P)*32768 + bb1 + n * 2048);     \
    }                                                                           \
    gload16(pA00 + (P)*128, smem + ((P)^1)*32768 + wid * 1024);                 \
    gload16(pA01 + (P)*128, smem + ((P)^1)*32768 + 8192 + wid * 1024);          \
    asm volatile("s_waitcnt lgkmcnt(8)" ::: "memory");                          \
    __builtin_amdgcn_s_barrier();                                               \
    asm volatile("s_waitcnt lgkmcnt(0)" ::: "memory");                          \
    __builtin_amdgcn_sched_barrier(0);                                          \
    __builtin_amdgcn_s_setprio(1);                                              \
    MFMA8(0, 0, aC0, aC1, bL0, bL1)                                             \
    __builtin_amdgcn_s_setprio(0);                                              \
    __builtin_amdgcn_s_barrier();                                               \
    __builtin_amdgcn_sched_barrier(0);                                          \
    /* P2: read bHi (4 ds); stage A(t+1)h1 -> buf P^1 */                        \
    _Pragma("unroll") for (int n = 0; n < 2; ++n) {                             \
      bH0[n] = *(const bf16x8*)(smem + 65536 + (P)*32768 + bb0 + (2+n)*2048);   \
      bH1[n] = *(const bf16x8*)(smem + 65536 + (P)*32768 + bb1 + (2+n)*2048);   \
    }                                                                           \
    gload16(pA10 + (P)*128, smem + ((P)^1)*32768 + 16384 + wid * 1024);         \
    gload16(pA11 + (P)*128, smem + ((P)^1)*32768 + 24576 + wid * 1024);         \
    __builtin_amdgcn_s_barrier();                                               \
    asm volatile("s_waitcnt lgkmcnt(0)" ::: "memory");                          \
    __builtin_amdgcn_sched_barrier(0);                                          \
    __builtin_amdgcn_s_setprio(1);                                              \
    MFMA8(0, 2, aC0, aC1, bH0, bH1)                                             \
    __builtin_amdgcn_s_setprio(0);                                              \
    __builtin_amdgcn_s_barrier();                                               \
    __builtin_amdgcn_sched_barrier(0);                                          \
    /* P3: read a(m4-7) (8 ds); stage B(t+2)h0 -> buf P (B(t) reads retired */  \
    /* at P2's trailing barrier) */                                             \
    _Pragma("unroll") for (int m = 0; m < 4; ++m) {                             \
      aC0[m] = *(const bf16x8*)(smem + (P)*32768 + ab0 + 8192 + m * 2048);      \
      aC1[m] = *(const bf16x8*)(smem + (P)*32768 + ab1 + 8192 + m * 2048);      \
    }                                                                           \
    gload16(pB00 + (P)*128, smem + 65536 + (P)*32768 + wid * 1024);             \
    gload16(pB01 + (P)*128, smem + 65536 + (P)*32768 + 8192 + wid * 1024);      \
    __builtin_amdgcn_s_barrier();                                               \
    asm volatile("s_waitcnt lgkmcnt(0)" ::: "memory");                          \
    __builtin_amdgcn_sched_barrier(0);                                          \
    __builtin_amdgcn_s_setprio(1);                                              \
    MFMA8(4, 2, aC0, aC1, bH0, bH1)                                             \
    __builtin_amdgcn_s_setprio(0);                                              \
    __builtin_amdgcn_s_barrier();                                               \
    __builtin_amdgcn_sched_barrier(0);                                          \
    /* P4: stage B(t+2)h1; vmcnt(4) gate = tile t+1 fully landed */             \
    gload16(pB10 + (P)*128, smem + 65536 + (P)*32768 + 16384 + wid * 1024);     \
    gload16(pB11 + (P)*128, smem + 65536 + (P)*32768 + 24576 + wid * 1024);     \
    asm volatile("s_waitcnt vmcnt(4)" ::: "memory");                            \
    __builtin_amdgcn_s_barrier();                                               \
    __builtin_amdgcn_sched_barrier(0);                                          \
    __builtin_amdgcn_s_setprio(1);                                              \
    MFMA8(4, 0, aC0, aC1, bL0, bL1)                                             \
    __builtin_amdgcn_s_setprio(0);                                              \
    __builtin_amdgcn_s_barrier();                                               \
    __builtin_amdgcn_sched_barrier(0);                                          \
  }

template <int EPI, int MAP>
__global__ __launch_bounds__(512, 1) void gemm_kernel(
    const unsigned short* __restrict__ Ag, const unsigned short* __restrict__ Bg,
    int lda, int ldb, int niter, int kchunk,
    const float* __restrict__ comb, unsigned short* __restrict__ hout,
    float* __restrict__ pout) {
  __shared__ __align__(16) char smem[131072];  // A 2buf x 32KB | B 2buf x 32KB

  const int tid = threadIdx.x;
  const int lane = tid & 63;
  const int wid = tid >> 6;
  const int wr = wid >> 2;        // 0..1  (M half: 128 rows)
  const int wc = wid & 3;         // 0..3  (N quarter: 64 cols)

  int mt, nt, zt;
  {
    int bid = blockIdx.x;
    if (MAP == 0) {               // gemm1: XCD owns 6 N-panels, M fastest
      int xcd = bid & 7, r = bid >> 3;        // r in 0..47
      nt = xcd * 6 + (r >> 3); mt = r & 7; zt = 0;
    } else {                      // gemm2: XCD = K-split
      zt = bid & 7; int r = bid >> 3;         // r in 0..23
      nt = r % 3; mt = r / 3;
    }
  }
  const int rm0 = mt * 256;
  const int cn0 = nt * 256;
  const int kbeg = zt * kchunk;

  // ---- affine staging pointers (pre-swizzled source, rule #21) ----
  // gload (h,g) covers LDS rows h*128 + g*64 + (tid>>3), slot tid&7 (16B).
  auto gsrc = [&](const unsigned short* base, int ld, int row0, int h, int g) {
    int row = row0 + h * 128 + g * 64 + (tid >> 3);
    int scol = (((tid & 7) ^ ((tid >> 3) & 7)) << 4);
    return (const char*)base + ((size_t)row * ld + kbeg) * 2 + scol;
  };
  const char* pA00 = gsrc(Ag, lda, rm0, 0, 0);
  const char* pA01 = gsrc(Ag, lda, rm0, 0, 1);
  const char* pA10 = gsrc(Ag, lda, rm0, 1, 0);
  const char* pA11 = gsrc(Ag, lda, rm0, 1, 1);
  const char* pB00 = gsrc(Bg, ldb, cn0, 0, 0);
  const char* pB01 = gsrc(Bg, ldb, cn0, 0, 1);
  const char* pB10 = gsrc(Bg, ldb, cn0, 1, 0);
  const char* pB11 = gsrc(Bg, ldb, cn0, 1, 1);

  // ---- LDS read bases (bytes, buffer-relative) ----
  const int lswz = (lane & 7) << 4;
  const int colk0 = (((lane >> 4) & 3) * 16) ^ lswz;
  const int colk1 = (64 + ((lane >> 4) & 3) * 16) ^ lswz;
  const int ab0 = wr * 16384 + (lane & 15) * 128 + colk0;   // + m*2048 (+8192 hi)
  const int ab1 = wr * 16384 + (lane & 15) * 128 + colk1;
  const int bb0 = (wc >> 1) * 16384 + ((wc & 1) * 64 + (lane & 15)) * 128 + colk0;
  const int bb1 = (wc >> 1) * 16384 + ((wc & 1) * 64 + (lane & 15)) * 128 + colk1;

  f32x4 acc[8][4];
#pragma unroll
  for (int m = 0; m < 8; ++m)
#pragma unroll
    for (int n = 0; n < 4; ++n) acc[m][n] = (f32x4){0.f, 0.f, 0.f, 0.f};

  // ---- prologue: A(0),B(0),B(1) = 12 gloads; gate vmcnt(4) ----
  gload16(pA00, smem + wid * 1024);
  gload16(pA01, smem + 8192 + wid * 1024);
  gload16(pA10, smem + 16384 + wid * 1024);
  gload16(pA11, smem + 24576 + wid * 1024);
  gload16(pB00, smem + 65536 + wid * 1024);
  gload16(pB01, smem + 65536 + 8192 + wid * 1024);
  gload16(pB10, smem + 65536 + 16384 + wid * 1024);
  gload16(pB11, smem + 65536 + 24576 + wid * 1024);
  gload16(pB00 + 128, smem + 65536 + 32768 + wid * 1024);
  gload16(pB01 + 128, smem + 65536 + 32768 + 8192 + wid * 1024);
  gload16(pB10 + 128, smem + 65536 + 32768 + 16384 + wid * 1024);
  gload16(pB11 + 128, smem + 65536 + 32768 + 24576 + wid * 1024);
  pA00 += 128; pA01 += 128; pA10 += 128; pA11 += 128;   // -> A(1)
  pB00 += 256; pB01 += 256; pB10 += 256; pB11 += 256;   // -> B(2)
  asm volatile("s_waitcnt vmcnt(4)" ::: "memory");      // A(0),B(0) landed
  __builtin_amdgcn_s_barrier();
  __builtin_amdgcn_sched_barrier(0);

  bf16x8 aC0[4], aC1[4], bL0[2], bL1[2], bH0[2], bH1[2];
  for (int i = 0; i < niter; ++i) {
    KTILE(0)
    KTILE(1)
    pA00 += 256; pA01 += 256; pA10 += 256; pA11 += 256;
    pB00 += 256; pB01 += 256; pB10 += 256; pB11 += 256;
  }

  asm volatile("s_waitcnt vmcnt(0)" ::: "memory");  // drain tail stages
  __syncthreads();

  // ---- epilogue ----
  const int r0 = (lane >> 4) * 4;
  const int cl = lane & 15;
  if constexpr (EPI == 1) {
    float* Cwf = (float*)smem;   // reuse staging LDS: [256 rows][16 experts]
    {
      int row = tid >> 1, c8 = (tid & 1) * 8;
      const float* s = comb + (size_t)(rm0 + row) * N_EXP + c8;
      *(float4*)&Cwf[row * 16 + c8] = *(const float4*)s;
      *(float4*)&Cwf[row * 16 + c8 + 4] = *(const float4*)(s + 4);
    }
    __syncthreads();
#pragma unroll
    for (int n = 0; n < 4; ++n) {
      int colg = cn0 + wc * 64 + n * 16 + cl;
      int e = (colg < 4096) ? (colg >> 9) : (8 + ((colg - 4096) >> 10));
#pragma unroll
      for (int m = 0; m < 8; ++m) {
        int rl = wr * 128 + m * 16 + r0;
#pragma unroll
        for (int r = 0; r < 4; ++r) {
          float v = gelu_f(acc[m][n][r]) * Cwf[(rl + r) * 16 + e];
          hout[(size_t)(rm0 + rl + r) * W_TOT + colg] = f2bf(v);
        }
      }
    }
  } else {
    float* pz = pout + (size_t)zt * T_TOK * D_EMB;
#pragma unroll
    for (int n = 0; n < 4; ++n) {
      int colg = cn0 + wc * 64 + n * 16 + cl;
#pragma unroll
      for (int m = 0; m < 8; ++m) {
        int rl = wr * 128 + m * 16 + r0;
#pragma unroll
        for (int r = 0; r < 4; ++r)
          pz[(size_t)(rm0 + rl + r) * D_EMB + colg] = acc[m][n][r];
      }
    }
  }
}

__global__ __launch_bounds__(256) void reduce_kernel(
    const float* __restrict__ partial, float* __restrict__ out, int splits) {
  int i = (blockIdx.x * 256 + threadIdx.x) * 4;
  if (i >= T_TOK * D_EMB) return;
  float4 s = *(const float4*)(partial + i);
  for (int sp = 1; sp < splits; ++sp) {
    float4 v = *(const float4*)(partial + (size_t)sp * T_TOK * D_EMB + i);
    s.x += v.x; s.y += v.y; s.z += v.z; s.w += v.w;
  }
  *(float4*)(out + i) = s;
}

// ---------------- launcher ----------------

extern "C" void kernel_launch(void* const* d_in, const int* in_sizes, int n_in,
                              void* d_out, int out_size, void* d_ws, size_t ws_size,
                              hipStream_t stream) {
  const float* x = (const float*)d_in[0];
  const float* router_w = (const float*)d_in[1];
  const float* w1 = (const float*)d_in[2];
  const float* w2 = (const float*)d_in[3];
  float* out = (float*)d_out;

  char* ws = (char*)d_ws;
  size_t off = 0;
  auto alloc = [&](size_t bytes) {
    char* p = ws + off;
    off += (bytes + 255) & ~(size_t)255;
    return p;
  };
  unsigned short* xb  = (unsigned short*)alloc((size_t)T_TOK * D_EMB * 2);
  unsigned short* w1t = (unsigned short*)alloc((size_t)W_TOT * D_EMB * 2);
  unsigned short* w2t = (unsigned short*)alloc((size_t)D_EMB * W_TOT * 2);
  unsigned short* h   = (unsigned short*)alloc((size_t)T_TOK * W_TOT * 2);
  float* comb         = (float*)alloc((size_t)T_TOK * N_EXP * 4);

  const int splits = 8;                     // grid 192; kchunk 1536 (24 tiles)
  float* partial = (float*)alloc((size_t)splits * T_TOK * D_EMB * 4);
  int kchunk = W_TOT / splits;

  transpose_cvt_kernel<<<dim3(W_TOT / 32, D_EMB / 32), 256, 0, stream>>>(w1, w1t, D_EMB, W_TOT);
  transpose_cvt_kernel<<<dim3(D_EMB / 32, W_TOT / 32), 256, 0, stream>>>(w2, w2t, W_TOT, D_EMB);
  router_kernel<<<T_TOK / 4, 256, 0, stream>>>(x, router_w, comb, xb);

  // GEMM1: H = gelu(X W1) * comb ; grid 384 = 8 XCD x (6 N x 8 M); 12 tiles
  gemm_kernel<1, 0><<<384, 512, 0, stream>>>(
      xb, w1t, D_EMB, D_EMB, (D_EMB / 64) / 2, D_EMB, comb, h, nullptr);

  // GEMM2: OUT = H W2 ; grid 192 = 8 splits x (3 N x 8 M); 24 tiles
  gemm_kernel<0, 1><<<192, 512, 0, stream>>>(
      h, w2t, W_TOT, W_TOT, (kchunk / 64) / 2, kchunk, nullptr, nullptr, partial);

  reduce_kernel<<<(T_TOK * D_EMB) / 1024, 256, 0, stream>>>(partial, out, splits);
}

// Round 16
// 146.528 us; speedup vs baseline: 1.2235x; 1.2235x over previous
//
#include <hip/hip_runtime.h>
#include <hip/hip_bf16.h>

// MoE MLP: x[1,2048,768] fp32, router_w[16,768], w1[768,12288], w2[12288,768]
// out[1,2048,768] fp32.  Experts: 8x512 + 8x1024, top-8, normalized.
// Dense bf16 GEMMs (reference is dense+masked); comb folded into H.
// GEMM core: R8-proven 256xBN / BK=64 / 8-wave / counted-vmcnt 2-phase
// pipeline, parameterized by NB = BN/64 (B-frag pairs per wave).
//  - gemm1: NB=4 (BN=256): per-block staged 688->590KB, grid 512->384
//    (~1.5 staggered rounds vs 2 full) -> predicted 62 -> ~45us.
//  - gemm2: NB=3 (BN=192), splits=8, grid 256 -- EXACTLY R8 (proven 62us).
// Per tile: NB+4 loads in order [B0..B(NB-1),A0,A2 | A1,A3]; ph0 gate
// vmcnt(2), ph1 gate vmcnt(NB+2). XOR-swizzled LDS, setprio, affine ptrs,
// unconditional tail stage (lands in adjacent ws regions, never read).

#define T_TOK 2048
#define D_EMB 768
#define W_TOT 12288
#define N_EXP 16

typedef __attribute__((ext_vector_type(4))) float f32x4;
typedef __attribute__((ext_vector_type(8))) short bf16x8;

typedef __attribute__((address_space(1))) const unsigned int as1c_u32;
typedef __attribute__((address_space(3))) unsigned int as3_u32;

__device__ __forceinline__ void gload16(const void* g, void* l) {
  __builtin_amdgcn_global_load_lds((as1c_u32*)g, (as3_u32*)l, 16, 0, 0);
}

__device__ __forceinline__ unsigned short f2bf(float f) {
  __hip_bfloat16 h = __float2bfloat16(f);
  return *reinterpret_cast<unsigned short*>(&h);
}

__device__ __forceinline__ float gelu_f(float x) {
  // jax.nn.gelu default (approximate=True, tanh form)
  float x3 = x * x * x;
  float a = 0.7978845608028654f * __builtin_fmaf(0.044715f, x3, x);
  a = fminf(fmaxf(a, -20.f), 20.f);
  float e = __expf(-2.0f * a);
  float t = (1.0f - e) / (1.0f + e);
  return 0.5f * x * (1.0f + t);
}

// in fp32 [R][C] -> out bf16 [C][R]
__global__ __launch_bounds__(256) void transpose_cvt_kernel(
    const float* __restrict__ in, unsigned short* __restrict__ out, int R, int C) {
  __shared__ float tile[32][33];
  int c0 = blockIdx.x * 32;
  int r0 = blockIdx.y * 32;
  int i = threadIdx.x;
  {
    int r = i >> 3, c4 = (i & 7) * 4;
    float4 v = *(const float4*)(in + (size_t)(r0 + r) * C + c0 + c4);
    tile[r][c4 + 0] = v.x; tile[r][c4 + 1] = v.y;
    tile[r][c4 + 2] = v.z; tile[r][c4 + 3] = v.w;
  }
  __syncthreads();
  {
    int c = i >> 3, r4 = (i & 7) * 4;
    ushort4 o;
    o.x = f2bf(tile[r4 + 0][c]);
    o.y = f2bf(tile[r4 + 1][c]);
    o.z = f2bf(tile[r4 + 2][c]);
    o.w = f2bf(tile[r4 + 3][c]);
    *(ushort4*)(out + (size_t)(c0 + c) * R + r0 + r4) = o;
  }
}

// ---------------- router (also emits xb = bf16(x)) ----------------

__global__ __launch_bounds__(256) void router_kernel(
    const float* __restrict__ x, const float* __restrict__ rw,
    float* __restrict__ comb, unsigned short* __restrict__ xbout) {
  int tid = threadIdx.x, lane = tid & 63, w = tid >> 6;
  int t = blockIdx.x * 4 + w;
  const float* xr = x + (size_t)t * D_EMB;
  float xv[12];
#pragma unroll
  for (int i = 0; i < 12; ++i) xv[i] = xr[lane + 64 * i];
#pragma unroll
  for (int i = 0; i < 12; ++i)
    xbout[(size_t)t * D_EMB + lane + 64 * i] = f2bf(xv[i]);
  float lg[16];
#pragma unroll
  for (int e = 0; e < 16; ++e) {
    const float* we = rw + (size_t)e * D_EMB;
    float p = 0.f;
#pragma unroll
    for (int i = 0; i < 12; ++i) p = __builtin_fmaf(xv[i], we[lane + 64 * i], p);
#pragma unroll
    for (int off = 32; off >= 1; off >>= 1) p += __shfl_xor(p, off, 64);
    lg[e] = p;
  }
  float mx = lg[0];
#pragma unroll
  for (int e = 1; e < 16; ++e) mx = fmaxf(mx, lg[e]);
  float ex[16];
#pragma unroll
  for (int e = 0; e < 16; ++e) ex[e] = __expf(lg[e] - mx);
  float selsum = 0.f, myval = 0.f;
#pragma unroll
  for (int e = 0; e < 16; ++e) {
    int rank = 0;
#pragma unroll
    for (int e2 = 0; e2 < 16; ++e2)
      rank += (ex[e2] > ex[e]) || (ex[e2] == ex[e] && e2 < e);
    bool sel = rank < 8;
    float v = sel ? ex[e] : 0.f;
    selsum += v;
    if (e == lane) myval = v;
  }
  if (lane < 16) comb[(size_t)t * N_EXP + lane] = myval / selsum;
}

// ------------- 8-wave counted-vmcnt pipelined GEMM, 256 x (NB*64) -------------
// Per K-tile: NB+4 loads in order [B0..B(NB-1),A0,A2 | A1,A3]; phase0 waits
// vmcnt(2) (B*,A0,A2 of cur landed), phase1 waits vmcnt(NB+2) (A1,A3 landed).
// Loads issued in tile t are consumed in tile t+1 (never drain to 0).
// MAP: 0 = gemm1 XCD-owns-N (grid 384: 8 XCD x 6 N x 8 M).
//      1 = gemm2 XCD=zt (grid 256: 8 splits x 4 N x 8 M).
// EPI: 1 = gelu*comb -> bf16 H, 0 = fp32 partial.

template <int EPI, int MAP, int NB>
__global__ __launch_bounds__(512, 1) void gemm_kernel(
    const unsigned short* __restrict__ Ag, const unsigned short* __restrict__ Bg,
    int lda, int ldb, int ntiles, int kchunk,
    const float* __restrict__ comb, unsigned short* __restrict__ hout,
    float* __restrict__ pout) {
  __shared__ __align__(16) char smem[65536 + 2 * NB * 8192];  // A 2x32KB | B 2xNBx8KB
  constexpr int BSTR = NB * 8192;

  const int tid = threadIdx.x;
  const int lane = tid & 63;
  const int wid = tid >> 6;
  const int wr = wid >> 2;        // 0..1  (M half: 128 rows)
  const int wc = wid & 3;         // 0..3  (N quarter: NB*16 cols)

  int mt, nt, zt;
  {
    int bid = blockIdx.x;
    if (MAP == 0) {               // gemm1: XCD owns 6 N-panels, M fastest
      int xcd = bid & 7, r = bid >> 3;        // r in 0..47
      nt = xcd * 6 + (r >> 3); mt = r & 7; zt = 0;
    } else {                      // gemm2: XCD = K-split
      zt = bid & 7; int r = bid >> 3;
      nt = r & 3; mt = r >> 2;
    }
  }
  const int rm0 = mt * 256;
  const int cn0 = nt * (NB * 64);
  const int kbeg = zt * kchunk;

  // ---- affine staging pointers at tile 0 (pre-swizzled source, rule #21) ----
  auto gsrc = [&](const unsigned short* base, int ld, int row0, int j) {
    int off = j * 8192 + tid * 16;
    int row = off >> 7, inrow = off & 127;
    int scol = inrow ^ ((row & 7) << 4);
    return (const char*)base + ((size_t)(row0 + row) * ld + kbeg) * 2 + scol;
  };
  const char* pA[4];
#pragma unroll
  for (int j = 0; j < 4; ++j) pA[j] = gsrc(Ag, lda, rm0, j);
  const char* pB[NB];
#pragma unroll
  for (int j = 0; j < NB; ++j) pB[j] = gsrc(Bg, ldb, cn0, j);

  // ---- precomputed LDS read base offsets (bytes, buffer 0) ----
  const int lswz = (lane & 7) << 4;
  const int colk0 = (((lane >> 4) & 3) * 16) ^ lswz;
  const int colk1 = (64 + ((lane >> 4) & 3) * 16) ^ lswz;
  const int abase0 = wr * 16384 + (lane & 15) * 128 + colk0;
  const int abase1 = wr * 16384 + (lane & 15) * 128 + colk1;
  const int bb0 = wc * (NB * 2048) + (lane & 15) * 128 + colk0;
  const int bb1 = wc * (NB * 2048) + (lane & 15) * 128 + colk1;

  f32x4 acc[8][NB];
#pragma unroll
  for (int m = 0; m < 8; ++m)
#pragma unroll
    for (int n = 0; n < NB; ++n) acc[m][n] = (f32x4){0.f, 0.f, 0.f, 0.f};

  // prologue: stage tile 0 into buf 0 (same issue order as steady state)
#pragma unroll
  for (int j = 0; j < NB; ++j)
    gload16(pB[j], smem + 65536 + j * 8192 + wid * 1024);
  gload16(pA[0], smem + wid * 1024);
  gload16(pA[2], smem + 16384 + wid * 1024);
  gload16(pA[1], smem + 8192 + wid * 1024);
  gload16(pA[3], smem + 24576 + wid * 1024);
#pragma unroll
  for (int j = 0; j < 4; ++j) pA[j] += 128;
#pragma unroll
  for (int j = 0; j < NB; ++j) pB[j] += 128;
  __builtin_amdgcn_sched_barrier(0);

  int aoff = 0, boff = 0;
  bf16x8 af[4], ag[4], bfr[NB], bgr[NB];
  for (int t = 0; t < ntiles; ++t) {
    const int adst = aoff ^ 32768;
    const int bdst = boff ^ BSTR;

    // ---- phase 0: m0-3 x all n ----
    asm volatile("s_waitcnt vmcnt(2)" ::: "memory");  // B*,A0,A2 of cur landed
    __builtin_amdgcn_s_barrier();
    __builtin_amdgcn_sched_barrier(0);
#pragma unroll
    for (int m = 0; m < 4; ++m) {
      af[m] = *(const bf16x8*)(smem + aoff + abase0 + m * 2048);
      ag[m] = *(const bf16x8*)(smem + aoff + abase1 + m * 2048);
    }
#pragma unroll
    for (int n = 0; n < NB; ++n) {
      bfr[n] = *(const bf16x8*)(smem + 65536 + boff + bb0 + n * 2048);
      bgr[n] = *(const bf16x8*)(smem + 65536 + boff + bb1 + n * 2048);
    }
    // stage tile t+1 (pointers already advanced to t+1)
#pragma unroll
    for (int j = 0; j < NB; ++j)
      gload16(pB[j], smem + 65536 + bdst + j * 8192 + wid * 1024);
    gload16(pA[0], smem + adst + wid * 1024);
    gload16(pA[2], smem + adst + 16384 + wid * 1024);
    __builtin_amdgcn_sched_barrier(0);
    __builtin_amdgcn_s_setprio(1);
#pragma unroll
    for (int m = 0; m < 4; ++m)
#pragma unroll
      for (int n = 0; n < NB; ++n) {
        acc[m][n] = __builtin_amdgcn_mfma_f32_16x16x32_bf16(af[m], bfr[n], acc[m][n], 0, 0, 0);
        acc[m][n] = __builtin_amdgcn_mfma_f32_16x16x32_bf16(ag[m], bgr[n], acc[m][n], 0, 0, 0);
      }
    __builtin_amdgcn_s_setprio(0);

    // ---- phase 1: m4-7 x all n ----
    if constexpr (NB == 3)
      asm volatile("s_waitcnt vmcnt(5)" ::: "memory");  // A1,A3 of cur landed
    else
      asm volatile("s_waitcnt vmcnt(6)" ::: "memory");
    __builtin_amdgcn_s_barrier();
    __builtin_amdgcn_sched_barrier(0);
#pragma unroll
    for (int m = 0; m < 4; ++m) {
      af[m] = *(const bf16x8*)(smem + aoff + abase0 + 8192 + m * 2048);
      ag[m] = *(const bf16x8*)(smem + aoff + abase1 + 8192 + m * 2048);
    }
    gload16(pA[1], smem + adst + 8192 + wid * 1024);
    gload16(pA[3], smem + adst + 24576 + wid * 1024);
    __builtin_amdgcn_sched_barrier(0);
    __builtin_amdgcn_s_setprio(1);
#pragma unroll
    for (int m = 0; m < 4; ++m)
#pragma unroll
      for (int n = 0; n < NB; ++n) {
        acc[4 + m][n] = __builtin_amdgcn_mfma_f32_16x16x32_bf16(af[m], bfr[n], acc[4 + m][n], 0, 0, 0);
        acc[4 + m][n] = __builtin_amdgcn_mfma_f32_16x16x32_bf16(ag[m], bgr[n], acc[4 + m][n], 0, 0, 0);
      }
    __builtin_amdgcn_s_setprio(0);

#pragma unroll
    for (int j = 0; j < 4; ++j) pA[j] += 128;
#pragma unroll
    for (int j = 0; j < NB; ++j) pB[j] += 128;
    aoff = adst; boff = bdst;
  }

  asm volatile("s_waitcnt vmcnt(0)" ::: "memory");  // drain tail stages
  __syncthreads();

  // ---- epilogue ----
  const int r0 = (lane >> 4) * 4;
  const int cl = lane & 15;
  if constexpr (EPI == 1) {
    float* Cwf = (float*)smem;   // reuse staging LDS: [256 rows][16 experts]
    {
      int row = tid >> 1, c8 = (tid & 1) * 8;
      const float* s = comb + (size_t)(rm0 + row) * N_EXP + c8;
      *(float4*)&Cwf[row * 16 + c8] = *(const float4*)s;
      *(float4*)&Cwf[row * 16 + c8 + 4] = *(const float4*)(s + 4);
    }
    __syncthreads();
#pragma unroll
    for (int n = 0; n < NB; ++n) {
      int colg = cn0 + wc * (NB * 16) + n * 16 + cl;
      int e = (colg < 4096) ? (colg >> 9) : (8 + ((colg - 4096) >> 10));
#pragma unroll
      for (int m = 0; m < 8; ++m) {
        int rl = wr * 128 + m * 16 + r0;
#pragma unroll
        for (int r = 0; r < 4; ++r) {
          float v = gelu_f(acc[m][n][r]) * Cwf[(rl + r) * 16 + e];
          hout[(size_t)(rm0 + rl + r) * W_TOT + colg] = f2bf(v);
        }
      }
    }
  } else {
    float* pz = pout + (size_t)zt * T_TOK * D_EMB;
#pragma unroll
    for (int n = 0; n < NB; ++n) {
      int colg = cn0 + wc * (NB * 16) + n * 16 + cl;
#pragma unroll
      for (int m = 0; m < 8; ++m) {
        int rl = wr * 128 + m * 16 + r0;
#pragma unroll
        for (int r = 0; r < 4; ++r)
          pz[(size_t)(rm0 + rl + r) * D_EMB + colg] = acc[m][n][r];
      }
    }
  }
}

__global__ __launch_bounds__(256) void reduce_kernel(
    const float* __restrict__ partial, float* __restrict__ out, int splits) {
  int i = (blockIdx.x * 256 + threadIdx.x) * 4;
  if (i >= T_TOK * D_EMB) return;
  float4 s = *(const float4*)(partial + i);
  for (int sp = 1; sp < splits; ++sp) {
    float4 v = *(const float4*)(partial + (size_t)sp * T_TOK * D_EMB + i);
    s.x += v.x; s.y += v.y; s.z += v.z; s.w += v.w;
  }
  *(float4*)(out + i) = s;
}

// ---------------- launcher ----------------

extern "C" void kernel_launch(void* const* d_in, const int* in_sizes, int n_in,
                              void* d_out, int out_size, void* d_ws, size_t ws_size,
                              hipStream_t stream) {
  const float* x = (const float*)d_in[0];
  const float* router_w = (const float*)d_in[1];
  const float* w1 = (const float*)d_in[2];
  const float* w2 = (const float*)d_in[3];
  float* out = (float*)d_out;

  char* ws = (char*)d_ws;
  size_t off = 0;
  auto alloc = [&](size_t bytes) {
    char* p = ws + off;
    off += (bytes + 255) & ~(size_t)255;
    return p;
  };
  unsigned short* xb  = (unsigned short*)alloc((size_t)T_TOK * D_EMB * 2);
  unsigned short* w1t = (unsigned short*)alloc((size_t)W_TOT * D_EMB * 2);
  unsigned short* w2t = (unsigned short*)alloc((size_t)D_EMB * W_TOT * 2);
  unsigned short* h   = (unsigned short*)alloc((size_t)T_TOK * W_TOT * 2);
  float* comb         = (float*)alloc((size_t)T_TOK * N_EXP * 4);

  const int splits = 8;                     // grid 256; kchunk 1536 (24 tiles)
  float* partial = (float*)alloc((size_t)splits * T_TOK * D_EMB * 4);
  int kchunk = W_TOT / splits;

  transpose_cvt_kernel<<<dim3(W_TOT / 32, D_EMB / 32), 256, 0, stream>>>(w1, w1t, D_EMB, W_TOT);
  transpose_cvt_kernel<<<dim3(D_EMB / 32, W_TOT / 32), 256, 0, stream>>>(w2, w2t, W_TOT, D_EMB);
  router_kernel<<<T_TOK / 4, 256, 0, stream>>>(x, router_w, comb, xb);

  // GEMM1: H = gelu(X W1) * comb ; BN=256 ; grid 384 = 8 XCD x (6 N x 8 M)
  gemm_kernel<1, 0, 4><<<384, 512, 0, stream>>>(
      xb, w1t, D_EMB, D_EMB, D_EMB / 64, D_EMB, comb, h, nullptr);

  // GEMM2: OUT = H W2 ; BN=192 ; grid 256 = 8 splits x (4 N x 8 M) [R8 exact]
  gemm_kernel<0, 1, 3><<<256, 512, 0, stream>>>(
      h, w2t, W_TOT, W_TOT, kchunk / 64, kchunk, nullptr, nullptr, partial);

  reduce_kernel<<<(T_TOK * D_EMB) / 1024, 256, 0, stream>>>(partial, out, splits);
}